// Round 3
// baseline (1549.724 us; speedup 1.0000x reference)
//
#include <hip/hip_runtime.h>
#include <stdint.h>

#define E_ 3
#define C_ 2
#define N_ 2048
#define B_ 64
#define T_ 50
#define WIN_ 256
#define WOUT_ 256
#define U_ 512
#define BT_ (B_*T_)
#define BTP_ 3328

typedef unsigned short u16;
typedef unsigned int u32;
typedef __bf16 bf16x8 __attribute__((ext_vector_type(8)));
typedef float f32x4 __attribute__((ext_vector_type(4)));

#define NN_ (2048LL*2048LL)

__device__ __forceinline__ float bf2f(u16 u){
  u32 x = ((u32)u) << 16; return __builtin_bit_cast(float, x);
}
__device__ __forceinline__ u16 f2bf(float f){
  u32 x = __builtin_bit_cast(u32, f);
  u32 r = (x + 0x7fffu + ((x >> 16) & 1u)) >> 16;
  return (u16)r;
}

__device__ __forceinline__ void gload16(const u16* g, u16* l){
  __builtin_amdgcn_global_load_lds((const __attribute__((address_space(1))) u32*)g,
                                   (__attribute__((address_space(3))) u32*)l, 16, 0, 0);
}

// ---------------- softmax filters: filt[(fi*C+c)*E+e] ----------------
__global__ void k_filters(const float* __restrict__ w1, const float* __restrict__ w2,
                          const float* __restrict__ w3, float* __restrict__ filt){
  const int t = threadIdx.x;
  if(t >= 3*C_) return;
  const int fi = t / C_, c = t % C_;
  const float* w = (fi==0) ? w1 : ((fi==1) ? w2 : w3);
  float v[E_]; float mx = -3.4e38f;
  for(int e=0;e<E_;e++){ v[e] = w[c*E_+e]; mx = fmaxf(mx, v[e]); }
  float s = 0.f;
  for(int e=0;e<E_;e++){ v[e] = expf(v[e]-mx); s += v[e]; }
  for(int e=0;e<E_;e++) filt[(fi*C_+c)*E_ + e] = v[e]/s;
}

// ---------------- HA[c][n][m] = sum_e f[c][e]*A[e][n][m] ----------------
__global__ void k_combine(const float* __restrict__ A, const float* __restrict__ f,
                          u16* __restrict__ HA){
  const long i = (long)blockIdx.x*256 + threadIdx.x;
  const int c = blockIdx.y;
  float s = 0.f;
  #pragma unroll
  for(int e=0;e<E_;e++) s += f[c*E_+e]*A[e*NN_ + i];
  HA[c*NN_ + i] = f2bf(s);
}

// ---------------- out[c][m][k] = sum_e f[c][e]*A[e][k][m] ----------------
__global__ void k_combineT(const float* __restrict__ A, const float* __restrict__ f,
                           u16* __restrict__ outp){
  __shared__ float t2[32][33];
  const int c = blockIdx.z;
  const int ti = blockIdx.x, tj = blockIdx.y;
  const int x = threadIdx.x, y0 = threadIdx.y;
  float wv[E_];
  #pragma unroll
  for(int e=0;e<E_;e++) wv[e] = f[c*E_+e];
  #pragma unroll
  for(int i=0;i<4;i++){
    const int y = y0 + i*8;
    const long base = (long)(tj*32+y)*N_ + ti*32 + x;
    float s = 0.f;
    #pragma unroll
    for(int e=0;e<E_;e++) s += wv[e]*A[e*NN_ + base];
    t2[y][x] = s;
  }
  __syncthreads();
  #pragma unroll
  for(int i=0;i<4;i++){
    const int y = y0 + i*8;
    outp[c*NN_ + (long)(ti*32+y)*N_ + tj*32 + x] = f2bf(t2[x][y]);
  }
}

// ---------------- MFMA GEMM: OUT[i][j] = sum_k A[i][k]*B[j][k] ----------------
// MODE 1: bf16 raw; 2: bf16 relu(dis[row]*acc + bias[col]); 3: f32 acc + bias[col];
// MODE 4: Gxt transpose-scatter: Gxt[(t*2048+col)*64+b] = acc + bias[col], row=b*50+t
template<int MODE>
__global__ __launch_bounds__(256) void gemm_bt(
    const u16* __restrict__ Ag, const u16* __restrict__ Bg, void* __restrict__ Cg,
    int K, int ldc, long sA, long sB, long sC,
    const float* __restrict__ disv, int sDis, const float* __restrict__ bias)
{
  __shared__ u16 At[128*32];
  __shared__ u16 Bt[128*32];
  const int tid = threadIdx.x;
  const int w = tid >> 6, l = tid & 63;
  const int z = blockIdx.z;
  const u16* Ab = Ag + (long)z*sA;
  const u16* Bb = Bg + (long)z*sB;
  const int rowBase = blockIdx.y*128;
  const int colBase = blockIdx.x*128;

  f32x4 acc[4][4];
  #pragma unroll
  for(int i=0;i<4;i++)
    #pragma unroll
    for(int j=0;j<4;j++)
      acc[i][j] = f32x4{0.f,0.f,0.f,0.f};

  const int wr = w >> 1, wc = w & 1;
  const int arow0 = (w*2+0)*16 + (l>>2);
  const int arow1 = (w*2+1)*16 + (l>>2);
  const int kc = (l&3)*8;
  const int frow = l & 15;
  const int fk = (l>>4)*8;

  const int nk = K >> 5;
  for(int kt=0; kt<nk; ++kt){
    const int k0 = kt << 5;
    gload16(Ab + (long)(rowBase+arow0)*K + k0 + kc, &At[(w*2+0)*512]);
    gload16(Ab + (long)(rowBase+arow1)*K + k0 + kc, &At[(w*2+1)*512]);
    gload16(Bb + (long)(colBase+arow0)*K + k0 + kc, &Bt[(w*2+0)*512]);
    gload16(Bb + (long)(colBase+arow1)*K + k0 + kc, &Bt[(w*2+1)*512]);
    __syncthreads();
    bf16x8 af[4], bfv[4];
    #pragma unroll
    for(int m=0;m<4;m++)
      af[m] = *(const bf16x8*)&At[(wr*64 + m*16 + frow)*32 + fk];
    #pragma unroll
    for(int n=0;n<4;n++)
      bfv[n] = *(const bf16x8*)&Bt[(wc*64 + n*16 + frow)*32 + fk];
    #pragma unroll
    for(int m=0;m<4;m++)
      #pragma unroll
      for(int n=0;n<4;n++)
        acc[m][n] = __builtin_amdgcn_mfma_f32_16x16x32_bf16(af[m], bfv[n], acc[m][n], 0, 0, 0);
    __syncthreads();
  }

  #pragma unroll
  for(int m=0;m<4;m++){
    const int row0 = rowBase + wr*64 + m*16 + (l>>4)*4;
    #pragma unroll
    for(int n=0;n<4;n++){
      const int col = colBase + wc*64 + n*16 + (l&15);
      #pragma unroll
      for(int r=0;r<4;r++){
        const float v = acc[m][n][r];
        if(MODE==1){
          ((u16*)Cg)[z*sC + (long)(row0+r)*ldc + col] = f2bf(v);
        } else if(MODE==2){
          float o = disv[z*(long)sDis + row0 + r]*v + bias[col];
          o = o > 0.f ? o : 0.f;
          ((u16*)Cg)[z*sC + (long)(row0+r)*ldc + col] = f2bf(o);
        } else if(MODE==3){
          ((float*)Cg)[z*sC + (long)(row0+r)*ldc + col] = v + bias[col];
        } else if(MODE==4){
          const int row = row0 + r;           // bt index
          if(row < BT_){
            const int bb = row/50, tt = row - bb*50;
            ((float*)Cg)[((long)tt*2048 + col)*64 + bb] = v + bias[col];
          }
        }
      }
    }
  }
}

// ---------------- col-normalize H in place (bf16), zero diag ----------------
__global__ void k_colnorm(u16* __restrict__ H){
  const int c = blockIdx.y;
  const int m = blockIdx.x*256 + threadIdx.x;
  u16* Hc = H + c*NN_;
  float deg = 0.f;
  for(int n=0;n<N_;n++){
    if(n != m) deg += bf2f(Hc[(long)n*N_ + m]);
  }
  const float dinv = deg > 0.f ? 1.f/deg : 0.f;
  for(int n=0;n<N_;n++){
    const long idx = (long)n*N_ + m;
    Hc[idx] = f2bf(n==m ? 0.f : bf2f(Hc[idx])*dinv);
  }
}

// ---------------- dis[c][j] = rsqrt(1 + rowsum(H2t[c][j][:])) ----------------
__global__ void k_gcnprep(const u16* __restrict__ H2t, float* __restrict__ disv){
  const int c = blockIdx.y, j = blockIdx.x;
  const u16* r = H2t + (c*(long)N_ + j)*N_;
  float s = 0.f;
  for(int i=threadIdx.x;i<N_;i+=256) s += bf2f(r[i]);
  __shared__ float red[256];
  red[threadIdx.x] = s;
  __syncthreads();
  for(int st=128; st>0; st>>=1){
    if(threadIdx.x < st) red[threadIdx.x] += red[threadIdx.x+st];
    __syncthreads();
  }
  if(threadIdx.x==0){
    const float deg = red[0] + 1.f;
    disv[c*N_ + j] = deg > 0.f ? rsqrtf(deg) : 0.f;
  }
}

// ---------------- Pd[c][j][i] = (H2t + I) * dis[i] ----------------
__global__ void k_pd(const u16* __restrict__ H2t, const float* __restrict__ disv,
                     u16* __restrict__ Pd){
  const long i = (long)blockIdx.x*256 + threadIdx.x;
  const int c = blockIdx.y;
  const int j = (int)(i >> 11);
  const int ii = (int)(i & (N_-1));
  const long idx = c*NN_ + i;
  const float v = bf2f(H2t[idx]) + (ii==j ? 1.f : 0.f);
  Pd[idx] = f2bf(v*disv[c*N_ + ii]);
}

// ---------------- transpose f32 in[R][Cc] -> bf16 out[Cc][R] ----------------
__global__ void k_transpose(const float* __restrict__ in, u16* __restrict__ out,
                            int R, int Cc){
  __shared__ float tt[32][33];
  const int ti = blockIdx.x, tj = blockIdx.y;
  const int x = threadIdx.x, y0 = threadIdx.y;
  #pragma unroll
  for(int i=0;i<4;i++){
    const int y = y0 + i*8;
    tt[y][x] = in[(long)(tj*32+y)*Cc + ti*32 + x];
  }
  __syncthreads();
  #pragma unroll
  for(int i=0;i<4;i++){
    const int y = y0 + i*8;
    out[(long)(ti*32+y)*R + tj*32 + x] = f2bf(tt[x][y]);
  }
}

// ---------------- cast f32 -> bf16 ----------------
__global__ void k_cast(const float* __restrict__ in, u16* __restrict__ out){
  const long i = (long)blockIdx.x*256 + threadIdx.x;
  out[i] = f2bf(in[i]);
}

// ---------------- bsum = bih + bhh ----------------
__global__ void k_bias(const float* __restrict__ bih, const float* __restrict__ bhh,
                       float* __restrict__ bsum){
  const int i = blockIdx.x*256 + threadIdx.x;
  bsum[i] = bih[i] + bhh[i];
}

// ---------------- basket max-pool via active list ----------------
__global__ void k_pool(const float* __restrict__ seqs, const float* __restrict__ X_,
                       u16* __restrict__ bs){
  const int t = blockIdx.x, b = blockIdx.y;
  const float* mask = seqs + ((long)b*T_ + t)*N_;
  const int f = threadIdx.x;
  __shared__ int list[N_];
  __shared__ int cnt;
  if(f==0) cnt = 0;
  __syncthreads();
  for(int n0=f; n0<N_; n0+=256){
    if(mask[n0] > 0.f){
      int p = atomicAdd(&cnt, 1);
      list[p] = n0;
    }
  }
  __syncthreads();
  const int m = cnt;
  float mx = -3.4e38f;
  for(int i=0;i<m;i++)
    mx = fmaxf(mx, X_[(long)list[i]*WOUT_ + f]);
  bs[((long)b*T_ + t)*WOUT_ + f] = f2bf(m>0 ? mx : 0.f);
}

__global__ void k_zeropad(u16* __restrict__ bs){
  const int i = blockIdx.x*256 + threadIdx.x;
  bs[(long)BT_*WOUT_ + i] = 0;
}

// ---------------- pack Whh for k_step ----------------
// block g, local row lr = ui*4+gam (ui=0..15, gam=gate), global row = gam*512+g*16+ui
// swizzle: element e holds k = e ^ ((lr&7)<<3)
__global__ void k_packWhh2(const float* __restrict__ Whh, u16* __restrict__ P){
  const long idx = (long)blockIdx.x*256 + threadIdx.x;  // 0..1048575
  const int e  = (int)(idx & 511);
  const int lr = (int)((idx >> 9) & 63);
  const int g  = (int)(idx >> 15);
  const int gam = lr & 3, ui = lr >> 2;
  const int grow = gam*512 + g*16 + ui;
  const int k = e ^ ((lr & 7) << 3);
  P[idx] = f2bf(Whh[(long)grow*512 + k]);
}

// ---------------- Hbuf init: Hb[b*512 + (u ^ ((b&7)<<3))] = h0[b][u] ----------------
__global__ void k_hinit(const float* __restrict__ h0, u16* __restrict__ Hb){
  const int idx = blockIdx.x*256 + threadIdx.x;  // 0..32767
  const int b = idx >> 9, u = idx & 511;
  Hb[(b << 9) + (u ^ ((b & 7) << 3))] = f2bf(h0[idx]);
}

// ---------------- LSTM step: 32 blocks x 256 thr, block g owns u in [g*16,g*16+16) ----------------
__global__ __launch_bounds__(256) void k_step(
    const u16* __restrict__ WhhB, const float* __restrict__ Gxt,
    const float* __restrict__ c0v, const int* __restrict__ seqlen,
    const u16* __restrict__ Hin, u16* __restrict__ Hout,
    float* __restrict__ Cbuf, float* __restrict__ act, int t)
{
  __shared__ u16 Wl[64*512];
  __shared__ u16 Hl[64*512];
  const int g = blockIdx.x, tid = threadIdx.x;
  const int w = tid >> 6, l = tid & 63;
  const u16* Wsrc = WhhB + (long)g*(64*512);
  #pragma unroll
  for(int it=0; it<16; ++it){
    const int ch = it*4 + w;
    gload16(Wsrc + ch*512 + l*8, &Wl[ch*512]);
    gload16(Hin  + ch*512 + l*8, &Hl[ch*512]);
  }
  __syncthreads();

  f32x4 acc[4];
  #pragma unroll
  for(int n=0;n<4;n++) acc[n] = f32x4{0.f,0.f,0.f,0.f};
  const int frow = l & 15, fk = (l>>4)*8;
  const int lr = w*16 + frow;               // local gate-row for A frag
  #pragma unroll
  for(int kk=0; kk<16; ++kk){
    const int ke = kk*32 + fk;
    bf16x8 a = *(const bf16x8*)&Wl[lr*512 + (ke ^ ((lr&7)<<3))];
    #pragma unroll
    for(int n=0;n<4;n++){
      const int b = n*16 + frow;
      bf16x8 bb = *(const bf16x8*)&Hl[b*512 + (ke ^ ((b&7)<<3))];
      acc[n] = __builtin_amdgcn_mfma_f32_16x16x32_bf16(a, bb, acc[n], 0, 0, 0);
    }
  }

  const int ui = w*4 + (l>>4);              // 0..15
  const int ug = g*16 + ui;                 // global u
  const float* gx = Gxt + (long)t*2048*64;
  #pragma unroll
  for(int n=0;n<4;n++){
    const int b = n*16 + (l&15);
    const float a0 = acc[n][0] + gx[(0*512+ug)*64 + b];
    const float a1 = acc[n][1] + gx[(1*512+ug)*64 + b];
    const float a2 = acc[n][2] + gx[(2*512+ug)*64 + b];
    const float a3 = acc[n][3] + gx[(3*512+ug)*64 + b];
    const float cprev = (t==0) ? c0v[b*512 + ug] : Cbuf[(g*256 + tid)*4 + n];
    const float ig = 1.f/(1.f + expf(-a0));
    const float fg = 1.f/(1.f + expf(-a1));
    const float gg = tanhf(a2);
    const float og = 1.f/(1.f + expf(-a3));
    const float c = fg*cprev + ig*gg;
    const float h = og*tanhf(c);
    Cbuf[(g*256 + tid)*4 + n] = c;
    Hout[(b << 9) + (ug ^ ((b & 7) << 3))] = f2bf(h);
    if(seqlen[b] - 1 == t) act[b*512 + ug] = h;
  }
}

// ---------------- out[b][n] = sigmoid(actual[b] . sWt[:,n])  (f32 out!) ----------------
__global__ void k_score(const float* __restrict__ actual, const u16* __restrict__ sWt,
                        float* __restrict__ out){
  const int n = blockIdx.x*256 + threadIdx.x;
  const int b = blockIdx.y;
  const float* ab = actual + (long)b*U_;
  float s = 0.f;
  for(int uu=0; uu<U_; uu++) s += ab[uu]*bf2f(sWt[(long)uu*N_ + n]);
  out[(long)b*N_ + n] = 1.f/(1.f + expf(-s));
}

extern "C" void kernel_launch(void* const* d_in, const int* in_sizes, int n_in,
                              void* d_out, int out_size, void* d_ws, size_t ws_size,
                              hipStream_t stream){
  (void)in_sizes; (void)n_in; (void)out_size; (void)ws_size;
  const float* A      = (const float*)d_in[0];
  const float* X      = (const float*)d_in[1];
  const float* seqs   = (const float*)d_in[2];
  const int*   seqlen = (const int*)d_in[3];
  const float* h0     = (const float*)d_in[4];
  const float* c0     = (const float*)d_in[5];
  const float* gtw1   = (const float*)d_in[6];
  const float* gtw2   = (const float*)d_in[7];
  const float* gtw3   = (const float*)d_in[8];
  const float* gcnW   = (const float*)d_in[9];
  const float* gcnB   = (const float*)d_in[10];
  const float* lin1W  = (const float*)d_in[11];
  const float* lin1B  = (const float*)d_in[12];
  const float* Wih    = (const float*)d_in[13];
  const float* Whh    = (const float*)d_in[14];
  const float* bihp   = (const float*)d_in[15];
  const float* bhhp   = (const float*)d_in[16];
  const float* scoreW = (const float*)d_in[17];

  char* ws = (char*)d_ws;
  u16* buf0 = (u16*)(ws + 0);
  u16* buf1 = (u16*)(ws + 16777216);
  u16* buf2 = (u16*)(ws + 33554432);
  char* S0  = ws + 50331648;
  float* filt  = (float*)(S0 + 0);
  float* disv  = (float*)(S0 + 1024);
  u16*  Wt     = (u16*) (S0 + 17408);
  u16*  XWt    = (u16*) (S0 + 148480);
  u16*  catb   = (u16*) (S0 + 1197056);
  u16*  l1Wt   = (u16*) (S0 + 3294208);
  float* Xo    = (float*)(S0 + 3556352);
  u16*  bs     = (u16*) (S0 + 5653504);
  float* act   = (float*)(S0 + 7357440);
  u16*  sWt    = (u16*) (S0 + 7488512);
  u16*  WhhB   = (u16*) (S0 + 9585664);
  u16*  Xbf    = (u16*) (S0 + 11682816);
  u16*  Wihbf  = (u16*) (S0 + 12731392);
  float* bsum  = (float*)(S0 + 13779968);
  u16*  Hbuf0  = (u16*) (S0 + 13788160);
  u16*  Hbuf1  = (u16*) (S0 + 13853696);
  float* Cbuf  = (float*)(S0 + 13919232);
  // lifetimes: buf0: HA -> HB2t; buf1: HBt -> H2t/Pd; buf2: Hb/Hn; Gxt over buf0+buf1
  u16* HA   = buf0;
  u16* HBt  = buf1;
  u16* Hb   = buf2;
  u16* HB2t = buf0;
  u16* H2t  = buf1;
  u16* Pd   = buf1;
  float* Gxt = (float*)ws;   // 26.2 MiB, after buf0/buf1 dead

  k_filters<<<1, 64, 0, stream>>>(gtw1, gtw2, gtw3, filt);
  k_combine<<<dim3(NN_/256, C_), 256, 0, stream>>>(A, filt, HA);
  k_combineT<<<dim3(N_/32, N_/32, C_), dim3(32,8), 0, stream>>>(A, filt + C_*E_, HBt);
  k_transpose<<<dim3(WOUT_/32, WIN_/32), dim3(32,8), 0, stream>>>(gcnW, Wt, WIN_, WOUT_);
  k_transpose<<<dim3(WOUT_/32, (C_*WOUT_)/32), dim3(32,8), 0, stream>>>(lin1W, l1Wt, C_*WOUT_, WOUT_);
  k_transpose<<<dim3(U_/32, N_/32), dim3(32,8), 0, stream>>>(scoreW, sWt, N_, U_);
  k_cast<<<dim3((N_*WIN_)/256), 256, 0, stream>>>(X, Xbf);
  k_cast<<<dim3((4*U_*WOUT_)/256), 256, 0, stream>>>(Wih, Wihbf);
  k_bias<<<dim3((4*U_)/256), 256, 0, stream>>>(bihp, bhhp, bsum);
  // H = HA @ HB
  gemm_bt<1><<<dim3(16,16,C_), 256, 0, stream>>>(HA, HBt, Hb, N_, N_, NN_, NN_, NN_, nullptr, 0, nullptr);
  k_colnorm<<<dim3(N_/256, C_), 256, 0, stream>>>(Hb);
  k_combineT<<<dim3(N_/32, N_/32, C_), dim3(32,8), 0, stream>>>(A, filt + 2*C_*E_, HB2t);
  // H2t[m][n] = sum_k HB2t[m][k] * Hn[n][k]
  gemm_bt<1><<<dim3(16,16,C_), 256, 0, stream>>>(HB2t, Hb, H2t, N_, N_, NN_, NN_, NN_, nullptr, 0, nullptr);
  k_gcnprep<<<dim3(N_, C_), 256, 0, stream>>>(H2t, disv);
  k_pd<<<dim3(NN_/256, C_), 256, 0, stream>>>(H2t, disv, Pd);
  // XWt[f][node]
  gemm_bt<1><<<dim3(N_/128, WOUT_/128, 1), 256, 0, stream>>>(Wt, Xbf, XWt, WIN_, N_, 0, 0, 0, nullptr, 0, nullptr);
  // catb[t][c*256+f] = relu(dis[t]*(Pd x XWt) + gcn_b)
  gemm_bt<2><<<dim3(WOUT_/128, N_/128, C_), 256, 0, stream>>>(Pd, XWt, catb, N_, C_*WOUT_, NN_, 0, WOUT_, disv, N_, gcnB);
  // X_ = cat x lin1_W + lin1_b (f32)
  gemm_bt<3><<<dim3(WOUT_/128, N_/128, 1), 256, 0, stream>>>(catb, l1Wt, Xo, C_*WOUT_, WOUT_, 0, 0, 0, nullptr, 0, lin1B);
  k_zeropad<<<dim3((BTP_-BT_)*WOUT_/256), 256, 0, stream>>>(bs);
  k_pool<<<dim3(T_, B_), 256, 0, stream>>>(seqs, Xo, bs);
  // Gxt[(t*2048+r)*64+b] = bs[bt] . Wih[r] + bsum[r]
  gemm_bt<4><<<dim3((4*U_)/128, BTP_/128, 1), 256, 0, stream>>>(bs, Wihbf, Gxt, WOUT_, 0, 0, 0, 0, nullptr, 0, bsum);
  k_packWhh2<<<dim3(4096), 256, 0, stream>>>(Whh, WhhB);
  k_hinit<<<dim3(128), 256, 0, stream>>>(h0, Hbuf0);
  for(int t=0; t<T_; ++t){
    const u16* Hin = (t & 1) ? Hbuf1 : Hbuf0;
    u16* Hout      = (t & 1) ? Hbuf0 : Hbuf1;
    k_step<<<dim3(32), 256, 0, stream>>>(WhhB, Gxt, c0, seqlen, Hin, Hout, Cbuf, act, t);
  }
  k_score<<<dim3(N_/256, B_), 256, 0, stream>>>(act, sWt, (float*)d_out);
}

// Round 4
// 732.199 us; speedup vs baseline: 2.1165x; 2.1165x over previous
//
#include <hip/hip_runtime.h>
#include <stdint.h>

#define E_ 3
#define C_ 2
#define N_ 2048
#define B_ 64
#define T_ 50
#define WIN_ 256
#define WOUT_ 256
#define U_ 512
#define BT_ (B_*T_)
#define BTP_ 3328

typedef unsigned short u16;
typedef unsigned int u32;
typedef __bf16 bf16x8 __attribute__((ext_vector_type(8)));
typedef float f32x4 __attribute__((ext_vector_type(4)));

#define NN_ (2048LL*2048LL)

__device__ __forceinline__ float bf2f(u16 u){
  u32 x = ((u32)u) << 16; return __builtin_bit_cast(float, x);
}
__device__ __forceinline__ u16 f2bf(float f){
  u32 x = __builtin_bit_cast(u32, f);
  u32 r = (x + 0x7fffu + ((x >> 16) & 1u)) >> 16;
  return (u16)r;
}

__device__ __forceinline__ void gload16(const u16* g, u16* l){
  __builtin_amdgcn_global_load_lds((const __attribute__((address_space(1))) u32*)g,
                                   (__attribute__((address_space(3))) u32*)l, 16, 0, 0);
}

// ---------------- softmax filters: filt[(fi*C+c)*E+e] ----------------
__global__ void k_filters(const float* __restrict__ w1, const float* __restrict__ w2,
                          const float* __restrict__ w3, float* __restrict__ filt){
  const int t = threadIdx.x;
  if(t >= 3*C_) return;
  const int fi = t / C_, c = t % C_;
  const float* w = (fi==0) ? w1 : ((fi==1) ? w2 : w3);
  float v[E_]; float mx = -3.4e38f;
  for(int e=0;e<E_;e++){ v[e] = w[c*E_+e]; mx = fmaxf(mx, v[e]); }
  float s = 0.f;
  for(int e=0;e<E_;e++){ v[e] = expf(v[e]-mx); s += v[e]; }
  for(int e=0;e<E_;e++) filt[(fi*C_+c)*E_ + e] = v[e]/s;
}

// ---------------- HA[c][n][m] = sum_e f[c][e]*A[e][n][m] ----------------
__global__ void k_combine(const float* __restrict__ A, const float* __restrict__ f,
                          u16* __restrict__ HA){
  const long i = (long)blockIdx.x*256 + threadIdx.x;
  const int c = blockIdx.y;
  float s = 0.f;
  #pragma unroll
  for(int e=0;e<E_;e++) s += f[c*E_+e]*A[e*NN_ + i];
  HA[c*NN_ + i] = f2bf(s);
}

// ---------------- out[c][m][k] = sum_e f[c][e]*A[e][k][m] ----------------
__global__ void k_combineT(const float* __restrict__ A, const float* __restrict__ f,
                           u16* __restrict__ outp){
  __shared__ float t2[32][33];
  const int c = blockIdx.z;
  const int ti = blockIdx.x, tj = blockIdx.y;
  const int x = threadIdx.x, y0 = threadIdx.y;
  float wv[E_];
  #pragma unroll
  for(int e=0;e<E_;e++) wv[e] = f[c*E_+e];
  #pragma unroll
  for(int i=0;i<4;i++){
    const int y = y0 + i*8;
    const long base = (long)(tj*32+y)*N_ + ti*32 + x;
    float s = 0.f;
    #pragma unroll
    for(int e=0;e<E_;e++) s += wv[e]*A[e*NN_ + base];
    t2[y][x] = s;
  }
  __syncthreads();
  #pragma unroll
  for(int i=0;i<4;i++){
    const int y = y0 + i*8;
    outp[c*NN_ + (long)(ti*32+y)*N_ + tj*32 + x] = f2bf(t2[x][y]);
  }
}

// ---------------- MFMA GEMM: OUT[i][j] = sum_k A[i][k]*B[j][k] ----------------
// MODE 1: bf16 raw; 2: bf16 relu(dis[row]*acc + bias[col]); 3: f32 acc + bias[col];
// MODE 4: Gxt transpose-scatter: Gxt[(t*2048+col)*64+b] = acc + bias[col], row=b*50+t
template<int MODE>
__global__ __launch_bounds__(256) void gemm_bt(
    const u16* __restrict__ Ag, const u16* __restrict__ Bg, void* __restrict__ Cg,
    int K, int ldc, long sA, long sB, long sC,
    const float* __restrict__ disv, int sDis, const float* __restrict__ bias)
{
  __shared__ u16 At[128*32];
  __shared__ u16 Bt[128*32];
  const int tid = threadIdx.x;
  const int w = tid >> 6, l = tid & 63;
  const int z = blockIdx.z;
  const u16* Ab = Ag + (long)z*sA;
  const u16* Bb = Bg + (long)z*sB;
  const int rowBase = blockIdx.y*128;
  const int colBase = blockIdx.x*128;

  f32x4 acc[4][4];
  #pragma unroll
  for(int i=0;i<4;i++)
    #pragma unroll
    for(int j=0;j<4;j++)
      acc[i][j] = f32x4{0.f,0.f,0.f,0.f};

  const int wr = w >> 1, wc = w & 1;
  const int arow0 = (w*2+0)*16 + (l>>2);
  const int arow1 = (w*2+1)*16 + (l>>2);
  const int kc = (l&3)*8;
  const int frow = l & 15;
  const int fk = (l>>4)*8;

  const int nk = K >> 5;
  for(int kt=0; kt<nk; ++kt){
    const int k0 = kt << 5;
    gload16(Ab + (long)(rowBase+arow0)*K + k0 + kc, &At[(w*2+0)*512]);
    gload16(Ab + (long)(rowBase+arow1)*K + k0 + kc, &At[(w*2+1)*512]);
    gload16(Bb + (long)(colBase+arow0)*K + k0 + kc, &Bt[(w*2+0)*512]);
    gload16(Bb + (long)(colBase+arow1)*K + k0 + kc, &Bt[(w*2+1)*512]);
    __syncthreads();
    bf16x8 af[4], bfv[4];
    #pragma unroll
    for(int m=0;m<4;m++)
      af[m] = *(const bf16x8*)&At[(wr*64 + m*16 + frow)*32 + fk];
    #pragma unroll
    for(int n=0;n<4;n++)
      bfv[n] = *(const bf16x8*)&Bt[(wc*64 + n*16 + frow)*32 + fk];
    #pragma unroll
    for(int m=0;m<4;m++)
      #pragma unroll
      for(int n=0;n<4;n++)
        acc[m][n] = __builtin_amdgcn_mfma_f32_16x16x32_bf16(af[m], bfv[n], acc[m][n], 0, 0, 0);
    __syncthreads();
  }

  #pragma unroll
  for(int m=0;m<4;m++){
    const int row0 = rowBase + wr*64 + m*16 + (l>>4)*4;
    #pragma unroll
    for(int n=0;n<4;n++){
      const int col = colBase + wc*64 + n*16 + (l&15);
      #pragma unroll
      for(int r=0;r<4;r++){
        const float v = acc[m][n][r];
        if(MODE==1){
          ((u16*)Cg)[z*sC + (long)(row0+r)*ldc + col] = f2bf(v);
        } else if(MODE==2){
          float o = disv[z*(long)sDis + row0 + r]*v + bias[col];
          o = o > 0.f ? o : 0.f;
          ((u16*)Cg)[z*sC + (long)(row0+r)*ldc + col] = f2bf(o);
        } else if(MODE==3){
          ((float*)Cg)[z*sC + (long)(row0+r)*ldc + col] = v + bias[col];
        } else if(MODE==4){
          const int row = row0 + r;           // bt index
          if(row < BT_){
            const int bb = row/50, tt = row - bb*50;
            ((float*)Cg)[((long)tt*2048 + col)*64 + bb] = v + bias[col];
          }
        }
      }
    }
  }
}

// ---------------- column-degree partial sums: partial[c][chunk][col] ----------------
__global__ void k_degpart(const u16* __restrict__ H, float* __restrict__ partial){
  const int c = blockIdx.z;
  const int col = blockIdx.x*256 + threadIdx.x;
  const int r0 = blockIdx.y*128;
  const u16* Hc = H + c*NN_;
  float s = 0.f;
  #pragma unroll 4
  for(int r=0;r<128;r++) s += bf2f(Hc[(long)(r0+r)*N_ + col]);
  partial[((long)c*16 + blockIdx.y)*N_ + col] = s;
}

// ---------------- dinv[c][m] = 1/(colsum - diag), guarded ----------------
__global__ void k_dinv(const u16* __restrict__ H, const float* __restrict__ partial,
                       float* __restrict__ dinvb){
  const int i = blockIdx.x*256 + threadIdx.x;  // c*N+m
  const int c = i >> 11, m = i & (N_-1);
  float s = 0.f;
  #pragma unroll
  for(int p=0;p<16;p++) s += partial[((long)c*16 + p)*N_ + m];
  s -= bf2f(H[c*NN_ + (long)m*N_ + m]);
  dinvb[i] = s > 0.f ? 1.f/s : 0.f;
}

// ---------------- H[j][i] = (j==i) ? 0 : H*dinv[i]  (in place) ----------------
__global__ void k_colscale(u16* __restrict__ H, const float* __restrict__ dinvb){
  const long i = (long)blockIdx.x*256 + threadIdx.x;
  const int c = blockIdx.y;
  const int j = (int)(i >> 11), ii = (int)(i & (N_-1));
  const long idx = c*NN_ + i;
  const float v = (j==ii) ? 0.f : bf2f(H[idx])*dinvb[c*N_ + ii];
  H[idx] = f2bf(v);
}

// ---------------- dis[c][j] = rsqrt(1 + rowsum(H2t[c][j][:])) ----------------
__global__ void k_gcnprep(const u16* __restrict__ H2t, float* __restrict__ disv){
  const int c = blockIdx.y, j = blockIdx.x;
  const u16* r = H2t + (c*(long)N_ + j)*N_;
  float s = 0.f;
  for(int i=threadIdx.x;i<N_;i+=256) s += bf2f(r[i]);
  __shared__ float red[256];
  red[threadIdx.x] = s;
  __syncthreads();
  for(int st=128; st>0; st>>=1){
    if(threadIdx.x < st) red[threadIdx.x] += red[threadIdx.x+st];
    __syncthreads();
  }
  if(threadIdx.x==0){
    const float deg = red[0] + 1.f;
    disv[c*N_ + j] = deg > 0.f ? rsqrtf(deg) : 0.f;
  }
}

// ---------------- Pd[c][j][i] = (H2t + I) * dis[i] ----------------
__global__ void k_pd(const u16* __restrict__ H2t, const float* __restrict__ disv,
                     u16* __restrict__ Pd){
  const long i = (long)blockIdx.x*256 + threadIdx.x;
  const int c = blockIdx.y;
  const int j = (int)(i >> 11);
  const int ii = (int)(i & (N_-1));
  const long idx = c*NN_ + i;
  const float v = bf2f(H2t[idx]) + (ii==j ? 1.f : 0.f);
  Pd[idx] = f2bf(v*disv[c*N_ + ii]);
}

// ---------------- transpose f32 in[R][Cc] -> bf16 out[Cc][R] ----------------
__global__ void k_transpose(const float* __restrict__ in, u16* __restrict__ out,
                            int R, int Cc){
  __shared__ float tt[32][33];
  const int ti = blockIdx.x, tj = blockIdx.y;
  const int x = threadIdx.x, y0 = threadIdx.y;
  #pragma unroll
  for(int i=0;i<4;i++){
    const int y = y0 + i*8;
    tt[y][x] = in[(long)(tj*32+y)*Cc + ti*32 + x];
  }
  __syncthreads();
  #pragma unroll
  for(int i=0;i<4;i++){
    const int y = y0 + i*8;
    out[(long)(ti*32+y)*R + tj*32 + x] = f2bf(tt[x][y]);
  }
}

// ---------------- cast f32 -> bf16 ----------------
__global__ void k_cast(const float* __restrict__ in, u16* __restrict__ out){
  const long i = (long)blockIdx.x*256 + threadIdx.x;
  out[i] = f2bf(in[i]);
}

// ---------------- bsum = bih + bhh ----------------
__global__ void k_bias(const float* __restrict__ bih, const float* __restrict__ bhh,
                       float* __restrict__ bsum){
  const int i = blockIdx.x*256 + threadIdx.x;
  bsum[i] = bih[i] + bhh[i];
}

// ---------------- basket max-pool via active list ----------------
__global__ void k_pool(const float* __restrict__ seqs, const float* __restrict__ X_,
                       u16* __restrict__ bs){
  const int t = blockIdx.x, b = blockIdx.y;
  const float* mask = seqs + ((long)b*T_ + t)*N_;
  const int f = threadIdx.x;
  __shared__ int list[N_];
  __shared__ int cnt;
  if(f==0) cnt = 0;
  __syncthreads();
  for(int n0=f; n0<N_; n0+=256){
    if(mask[n0] > 0.f){
      int p = atomicAdd(&cnt, 1);
      list[p] = n0;
    }
  }
  __syncthreads();
  const int m = cnt;
  float mx = -3.4e38f;
  for(int i=0;i<m;i++)
    mx = fmaxf(mx, X_[(long)list[i]*WOUT_ + f]);
  bs[((long)b*T_ + t)*WOUT_ + f] = f2bf(m>0 ? mx : 0.f);
}

__global__ void k_zeropad(u16* __restrict__ bs){
  const int i = blockIdx.x*256 + threadIdx.x;
  bs[(long)BT_*WOUT_ + i] = 0;
}

// ---------------- pack Whh for k_step ----------------
__global__ void k_packWhh2(const float* __restrict__ Whh, u16* __restrict__ P){
  const long idx = (long)blockIdx.x*256 + threadIdx.x;  // 0..1048575
  const int e  = (int)(idx & 511);
  const int lr = (int)((idx >> 9) & 63);
  const int g  = (int)(idx >> 15);
  const int gam = lr & 3, ui = lr >> 2;
  const int grow = gam*512 + g*16 + ui;
  const int k = e ^ ((lr & 7) << 3);
  P[idx] = f2bf(Whh[(long)grow*512 + k]);
}

// ---------------- Hbuf init ----------------
__global__ void k_hinit(const float* __restrict__ h0, u16* __restrict__ Hb){
  const int idx = blockIdx.x*256 + threadIdx.x;  // 0..32767
  const int b = idx >> 9, u = idx & 511;
  Hb[(b << 9) + (u ^ ((b & 7) << 3))] = f2bf(h0[idx]);
}

// ---------------- LSTM step ----------------
__global__ __launch_bounds__(256) void k_step(
    const u16* __restrict__ WhhB, const float* __restrict__ Gxt,
    const float* __restrict__ c0v, const int* __restrict__ seqlen,
    const u16* __restrict__ Hin, u16* __restrict__ Hout,
    float* __restrict__ Cbuf, float* __restrict__ act, int t)
{
  __shared__ u16 Wl[64*512];
  __shared__ u16 Hl[64*512];
  const int g = blockIdx.x, tid = threadIdx.x;
  const int w = tid >> 6, l = tid & 63;
  const u16* Wsrc = WhhB + (long)g*(64*512);
  #pragma unroll
  for(int it=0; it<16; ++it){
    const int ch = it*4 + w;
    gload16(Wsrc + ch*512 + l*8, &Wl[ch*512]);
    gload16(Hin  + ch*512 + l*8, &Hl[ch*512]);
  }
  __syncthreads();

  f32x4 acc[4];
  #pragma unroll
  for(int n=0;n<4;n++) acc[n] = f32x4{0.f,0.f,0.f,0.f};
  const int frow = l & 15, fk = (l>>4)*8;
  const int lr = w*16 + frow;
  #pragma unroll
  for(int kk=0; kk<16; ++kk){
    const int ke = kk*32 + fk;
    bf16x8 a = *(const bf16x8*)&Wl[lr*512 + (ke ^ ((lr&7)<<3))];
    #pragma unroll
    for(int n=0;n<4;n++){
      const int b = n*16 + frow;
      bf16x8 bb = *(const bf16x8*)&Hl[b*512 + (ke ^ ((b&7)<<3))];
      acc[n] = __builtin_amdgcn_mfma_f32_16x16x32_bf16(a, bb, acc[n], 0, 0, 0);
    }
  }

  const int ui = w*4 + (l>>4);
  const int ug = g*16 + ui;
  const float* gx = Gxt + (long)t*2048*64;
  #pragma unroll
  for(int n=0;n<4;n++){
    const int b = n*16 + (l&15);
    const float a0 = acc[n][0] + gx[(0*512+ug)*64 + b];
    const float a1 = acc[n][1] + gx[(1*512+ug)*64 + b];
    const float a2 = acc[n][2] + gx[(2*512+ug)*64 + b];
    const float a3 = acc[n][3] + gx[(3*512+ug)*64 + b];
    const float cprev = (t==0) ? c0v[b*512 + ug] : Cbuf[(g*256 + tid)*4 + n];
    const float ig = 1.f/(1.f + expf(-a0));
    const float fg = 1.f/(1.f + expf(-a1));
    const float gg = tanhf(a2);
    const float og = 1.f/(1.f + expf(-a3));
    const float c = fg*cprev + ig*gg;
    const float h = og*tanhf(c);
    Cbuf[(g*256 + tid)*4 + n] = c;
    Hout[(b << 9) + (ug ^ ((b & 7) << 3))] = f2bf(h);
    if(seqlen[b] - 1 == t) act[b*512 + ug] = h;
  }
}

// ---------------- out[b][n] = sigmoid(actual[b] . sWt[:,n])  (f32 out) ----------------
__global__ void k_score(const float* __restrict__ actual, const u16* __restrict__ sWt,
                        float* __restrict__ out){
  const int n = blockIdx.x*256 + threadIdx.x;
  const int b = blockIdx.y;
  const float* ab = actual + (long)b*U_;
  float s = 0.f;
  for(int uu=0; uu<U_; uu++) s += ab[uu]*bf2f(sWt[(long)uu*N_ + n]);
  out[(long)b*N_ + n] = 1.f/(1.f + expf(-s));
}

extern "C" void kernel_launch(void* const* d_in, const int* in_sizes, int n_in,
                              void* d_out, int out_size, void* d_ws, size_t ws_size,
                              hipStream_t stream){
  (void)in_sizes; (void)n_in; (void)out_size; (void)ws_size;
  const float* A      = (const float*)d_in[0];
  const float* X      = (const float*)d_in[1];
  const float* seqs   = (const float*)d_in[2];
  const int*   seqlen = (const int*)d_in[3];
  const float* h0     = (const float*)d_in[4];
  const float* c0     = (const float*)d_in[5];
  const float* gtw1   = (const float*)d_in[6];
  const float* gtw2   = (const float*)d_in[7];
  const float* gtw3   = (const float*)d_in[8];
  const float* gcnW   = (const float*)d_in[9];
  const float* gcnB   = (const float*)d_in[10];
  const float* lin1W  = (const float*)d_in[11];
  const float* lin1B  = (const float*)d_in[12];
  const float* Wih    = (const float*)d_in[13];
  const float* Whh    = (const float*)d_in[14];
  const float* bihp   = (const float*)d_in[15];
  const float* bhhp   = (const float*)d_in[16];
  const float* scoreW = (const float*)d_in[17];

  char* ws = (char*)d_ws;
  u16* buf0 = (u16*)(ws + 0);
  u16* buf1 = (u16*)(ws + 16777216);
  u16* buf2 = (u16*)(ws + 33554432);
  char* S0  = ws + 50331648;
  float* filt  = (float*)(S0 + 0);
  float* disv  = (float*)(S0 + 1024);
  u16*  Wt     = (u16*) (S0 + 17408);
  u16*  XWt    = (u16*) (S0 + 148480);
  u16*  catb   = (u16*) (S0 + 1197056);
  u16*  l1Wt   = (u16*) (S0 + 3294208);
  float* Xo    = (float*)(S0 + 3556352);
  u16*  bs     = (u16*) (S0 + 5653504);
  float* act   = (float*)(S0 + 7357440);
  u16*  sWt    = (u16*) (S0 + 7488512);
  u16*  WhhB   = (u16*) (S0 + 9585664);
  u16*  Xbf    = (u16*) (S0 + 11682816);
  u16*  Wihbf  = (u16*) (S0 + 12731392);
  float* bsum  = (float*)(S0 + 13779968);
  u16*  Hbuf0  = (u16*) (S0 + 13788160);
  u16*  Hbuf1  = (u16*) (S0 + 13853696);
  float* Cbuf  = (float*)(S0 + 13919232);
  float* degp  = (float*)(S0 + 14050304);   // 2*16*2048*4 = 256 KB
  float* dinvb = (float*)(S0 + 14312448);   // 16 KB
  u16* HA   = buf0;
  u16* HBt  = buf1;
  u16* Hb   = buf2;
  u16* HB2t = buf0;
  u16* H2t  = buf1;
  u16* Pd   = buf1;
  float* Gxt = (float*)ws;   // 26.2 MiB, after buf0/buf1 dead

  k_filters<<<1, 64, 0, stream>>>(gtw1, gtw2, gtw3, filt);
  k_combine<<<dim3(NN_/256, C_), 256, 0, stream>>>(A, filt, HA);
  k_combineT<<<dim3(N_/32, N_/32, C_), dim3(32,8), 0, stream>>>(A, filt + C_*E_, HBt);
  k_transpose<<<dim3(WOUT_/32, WIN_/32), dim3(32,8), 0, stream>>>(gcnW, Wt, WIN_, WOUT_);
  k_transpose<<<dim3(WOUT_/32, (C_*WOUT_)/32), dim3(32,8), 0, stream>>>(lin1W, l1Wt, C_*WOUT_, WOUT_);
  k_transpose<<<dim3(U_/32, N_/32), dim3(32,8), 0, stream>>>(scoreW, sWt, N_, U_);
  k_cast<<<dim3((N_*WIN_)/256), 256, 0, stream>>>(X, Xbf);
  k_cast<<<dim3((4*U_*WOUT_)/256), 256, 0, stream>>>(Wih, Wihbf);
  k_bias<<<dim3((4*U_)/256), 256, 0, stream>>>(bihp, bhhp, bsum);
  // H = HA @ HB
  gemm_bt<1><<<dim3(16,16,C_), 256, 0, stream>>>(HA, HBt, Hb, N_, N_, NN_, NN_, NN_, nullptr, 0, nullptr);
  // col-normalize Hb (parallel): partial colsums -> dinv -> scale
  k_degpart<<<dim3(8, 16, C_), 256, 0, stream>>>(Hb, degp);
  k_dinv<<<dim3(16), 256, 0, stream>>>(Hb, degp, dinvb);
  k_colscale<<<dim3(NN_/256, C_), 256, 0, stream>>>(Hb, dinvb);
  k_combineT<<<dim3(N_/32, N_/32, C_), dim3(32,8), 0, stream>>>(A, filt + 2*C_*E_, HB2t);
  // H2t[m][n] = sum_k HB2t[m][k] * Hn[n][k]
  gemm_bt<1><<<dim3(16,16,C_), 256, 0, stream>>>(HB2t, Hb, H2t, N_, N_, NN_, NN_, NN_, nullptr, 0, nullptr);
  k_gcnprep<<<dim3(N_, C_), 256, 0, stream>>>(H2t, disv);
  k_pd<<<dim3(NN_/256, C_), 256, 0, stream>>>(H2t, disv, Pd);
  // XWt[f][node]
  gemm_bt<1><<<dim3(N_/128, WOUT_/128, 1), 256, 0, stream>>>(Wt, Xbf, XWt, WIN_, N_, 0, 0, 0, nullptr, 0, nullptr);
  // catb[t][c*256+f] = relu(dis[t]*(Pd x XWt) + gcn_b)
  gemm_bt<2><<<dim3(WOUT_/128, N_/128, C_), 256, 0, stream>>>(Pd, XWt, catb, N_, C_*WOUT_, NN_, 0, WOUT_, disv, N_, gcnB);
  // X_ = cat x lin1_W + lin1_b (f32)
  gemm_bt<3><<<dim3(WOUT_/128, N_/128, 1), 256, 0, stream>>>(catb, l1Wt, Xo, C_*WOUT_, WOUT_, 0, 0, 0, nullptr, 0, lin1B);
  k_zeropad<<<dim3((BTP_-BT_)*WOUT_/256), 256, 0, stream>>>(bs);
  k_pool<<<dim3(T_, B_), 256, 0, stream>>>(seqs, Xo, bs);
  // Gxt[(t*2048+r)*64+b] = bs[bt] . Wih[r] + bsum[r]
  gemm_bt<4><<<dim3((4*U_)/128, BTP_/128, 1), 256, 0, stream>>>(bs, Wihbf, Gxt, WOUT_, 0, 0, 0, 0, nullptr, 0, bsum);
  k_packWhh2<<<dim3(4096), 256, 0, stream>>>(Whh, WhhB);
  k_hinit<<<dim3(128), 256, 0, stream>>>(h0, Hbuf0);
  for(int t=0; t<T_; ++t){
    const u16* Hin = (t & 1) ? Hbuf1 : Hbuf0;
    u16* Hout      = (t & 1) ? Hbuf0 : Hbuf1;
    k_step<<<dim3(32), 256, 0, stream>>>(WhhB, Gxt, c0, seqlen, Hin, Hout, Cbuf, act, t);
  }
  k_score<<<dim3(N_/256, B_), 256, 0, stream>>>(act, sWt, (float*)d_out);
}

// Round 5
// 706.479 us; speedup vs baseline: 2.1936x; 1.0364x over previous
//
#include <hip/hip_runtime.h>
#include <stdint.h>

#define E_ 3
#define C_ 2
#define N_ 2048
#define B_ 64
#define T_ 50
#define WIN_ 256
#define WOUT_ 256
#define U_ 512
#define BT_ (B_*T_)
#define BTP_ 3328

typedef unsigned short u16;
typedef unsigned int u32;
typedef __bf16 bf16x8 __attribute__((ext_vector_type(8)));
typedef float f32x4 __attribute__((ext_vector_type(4)));

#define NN_ (2048LL*2048LL)

__device__ __forceinline__ float bf2f(u16 u){
  u32 x = ((u32)u) << 16; return __builtin_bit_cast(float, x);
}
__device__ __forceinline__ u16 f2bf(float f){
  u32 x = __builtin_bit_cast(u32, f);
  u32 r = (x + 0x7fffu + ((x >> 16) & 1u)) >> 16;
  return (u16)r;
}

__device__ __forceinline__ void gload16(const u16* g, u16* l){
  __builtin_amdgcn_global_load_lds((const __attribute__((address_space(1))) u32*)g,
                                   (__attribute__((address_space(3))) u32*)l, 16, 0, 0);
}

// ---------------- softmax filters: filt[(fi*C+c)*E+e] ----------------
__global__ void k_filters(const float* __restrict__ w1, const float* __restrict__ w2,
                          const float* __restrict__ w3, float* __restrict__ filt){
  const int t = threadIdx.x;
  if(t >= 3*C_) return;
  const int fi = t / C_, c = t % C_;
  const float* w = (fi==0) ? w1 : ((fi==1) ? w2 : w3);
  float v[E_]; float mx = -3.4e38f;
  for(int e=0;e<E_;e++){ v[e] = w[c*E_+e]; mx = fmaxf(mx, v[e]); }
  float s = 0.f;
  for(int e=0;e<E_;e++){ v[e] = expf(v[e]-mx); s += v[e]; }
  for(int e=0;e<E_;e++) filt[(fi*C_+c)*E_ + e] = v[e]/s;
}

// ---------------- fused combine: HA (direct, filt fi=0) + HBt (transposed, fi=1), A read ONCE ----------------
__global__ void k_combineAll(const float* __restrict__ A, const float* __restrict__ filt,
                             u16* __restrict__ HA, u16* __restrict__ HBt){
  __shared__ float te[3][32][33];
  const int ti = blockIdx.x, tj = blockIdx.y;
  const int x = threadIdx.x, y0 = threadIdx.y;
  #pragma unroll
  for(int i=0;i<4;i++){
    const int y = y0 + i*8;
    const long base = (long)(tj*32+y)*N_ + ti*32 + x;
    const float a0 = A[0*NN_+base], a1 = A[1*NN_+base], a2 = A[2*NN_+base];
    te[0][y][x]=a0; te[1][y][x]=a1; te[2][y][x]=a2;
    #pragma unroll
    for(int c=0;c<C_;c++)
      HA[c*NN_ + base] = f2bf(filt[c*E_]*a0 + filt[c*E_+1]*a1 + filt[c*E_+2]*a2);
  }
  __syncthreads();
  #pragma unroll
  for(int i=0;i<4;i++){
    const int y = y0 + i*8;
    const long ob = (long)(ti*32+y)*N_ + tj*32 + x;
    const float a0=te[0][x][y], a1=te[1][x][y], a2=te[2][x][y];
    #pragma unroll
    for(int c=0;c<C_;c++)
      HBt[c*NN_+ob] = f2bf(filt[(C_+c)*E_]*a0 + filt[(C_+c)*E_+1]*a1 + filt[(C_+c)*E_+2]*a2);
  }
}

// ---------------- HB2t both channels, one pass over A ----------------
__global__ void k_combineT2(const float* __restrict__ A, const float* __restrict__ f,
                            u16* __restrict__ outp){
  __shared__ float te[3][32][33];
  const int ti = blockIdx.x, tj = blockIdx.y;
  const int x = threadIdx.x, y0 = threadIdx.y;
  #pragma unroll
  for(int i=0;i<4;i++){
    const int y = y0 + i*8;
    const long base = (long)(tj*32+y)*N_ + ti*32 + x;
    te[0][y][x]=A[0*NN_+base]; te[1][y][x]=A[1*NN_+base]; te[2][y][x]=A[2*NN_+base];
  }
  __syncthreads();
  #pragma unroll
  for(int i=0;i<4;i++){
    const int y = y0 + i*8;
    const long ob = (long)(ti*32+y)*N_ + tj*32 + x;
    const float a0=te[0][x][y], a1=te[1][x][y], a2=te[2][x][y];
    #pragma unroll
    for(int c=0;c<C_;c++)
      outp[c*NN_+ob] = f2bf(f[c*E_]*a0 + f[c*E_+1]*a1 + f[c*E_+2]*a2);
  }
}

// ---------------- MFMA GEMM: OUT[i][j] = sum_k A[i][k]*B[j][k] ----------------
// LDS chunk-XOR swizzle: logical 8-elem chunk q of row r stored at position q^(r&3).
// MODE 1: bf16 raw; 2: bf16 relu(dis[row]*acc + bias[col]); 3: f32 acc + bias[col];
// MODE 4: Gxt transpose-scatter: Gxt[(t*2048+col)*64+b] = acc + bias[col], row=b*50+t
template<int MODE>
__global__ __launch_bounds__(256) void gemm_bt(
    const u16* __restrict__ Ag, const u16* __restrict__ Bg, void* __restrict__ Cg,
    int K, int ldc, long sA, long sB, long sC,
    const float* __restrict__ disv, int sDis, const float* __restrict__ bias)
{
  __shared__ u16 At[128*32];
  __shared__ u16 Bt[128*32];
  const int tid = threadIdx.x;
  const int w = tid >> 6, l = tid & 63;
  const int z = blockIdx.z;
  const u16* Ab = Ag + (long)z*sA;
  const u16* Bb = Bg + (long)z*sB;
  const int rowBase = blockIdx.y*128;
  const int colBase = blockIdx.x*128;

  f32x4 acc[4][4];
  #pragma unroll
  for(int i=0;i<4;i++)
    #pragma unroll
    for(int j=0;j<4;j++)
      acc[i][j] = f32x4{0.f,0.f,0.f,0.f};

  const int wr = w >> 1, wc = w & 1;
  const int arow0 = (w*2+0)*16 + (l>>2);
  const int arow1 = (w*2+1)*16 + (l>>2);
  // pre-swizzled global source chunk (rule 21: gload_lds dest stays linear)
  const int kc = (((l&3) ^ ((l>>2)&3)))*8;
  const int frow = l & 15;
  const int fkc = l >> 4;

  const int nk = K >> 5;
  for(int kt=0; kt<nk; ++kt){
    const int k0 = kt << 5;
    gload16(Ab + (long)(rowBase+arow0)*K + k0 + kc, &At[(w*2+0)*512]);
    gload16(Ab + (long)(rowBase+arow1)*K + k0 + kc, &At[(w*2+1)*512]);
    gload16(Bb + (long)(colBase+arow0)*K + k0 + kc, &Bt[(w*2+0)*512]);
    gload16(Bb + (long)(colBase+arow1)*K + k0 + kc, &Bt[(w*2+1)*512]);
    __syncthreads();
    bf16x8 af[4], bfv[4];
    #pragma unroll
    for(int m=0;m<4;m++){
      const int rr = wr*64 + m*16 + frow;
      af[m] = *(const bf16x8*)&At[rr*32 + ((fkc ^ (rr&3))<<3)];
    }
    #pragma unroll
    for(int n=0;n<4;n++){
      const int rr = wc*64 + n*16 + frow;
      bfv[n] = *(const bf16x8*)&Bt[rr*32 + ((fkc ^ (rr&3))<<3)];
    }
    #pragma unroll
    for(int m=0;m<4;m++)
      #pragma unroll
      for(int n=0;n<4;n++)
        acc[m][n] = __builtin_amdgcn_mfma_f32_16x16x32_bf16(af[m], bfv[n], acc[m][n], 0, 0, 0);
    __syncthreads();
  }

  #pragma unroll
  for(int m=0;m<4;m++){
    const int row0 = rowBase + wr*64 + m*16 + (l>>4)*4;
    #pragma unroll
    for(int n=0;n<4;n++){
      const int col = colBase + wc*64 + n*16 + (l&15);
      #pragma unroll
      for(int r=0;r<4;r++){
        const float v = acc[m][n][r];
        if(MODE==1){
          ((u16*)Cg)[z*sC + (long)(row0+r)*ldc + col] = f2bf(v);
        } else if(MODE==2){
          float o = disv[z*(long)sDis + row0 + r]*v + bias[col];
          o = o > 0.f ? o : 0.f;
          ((u16*)Cg)[z*sC + (long)(row0+r)*ldc + col] = f2bf(o);
        } else if(MODE==3){
          ((float*)Cg)[z*sC + (long)(row0+r)*ldc + col] = v + bias[col];
        } else if(MODE==4){
          const int row = row0 + r;           // bt index
          if(row < BT_){
            const int bb = row/50, tt = row - bb*50;
            ((float*)Cg)[((long)tt*2048 + col)*64 + bb] = v + bias[col];
          }
        }
      }
    }
  }
}

// ---------------- column-degree partial sums: partial[c][chunk][col] ----------------
__global__ void k_degpart(const u16* __restrict__ H, float* __restrict__ partial){
  const int c = blockIdx.z;
  const int col = blockIdx.x*256 + threadIdx.x;
  const int r0 = blockIdx.y*128;
  const u16* Hc = H + c*NN_;
  float s = 0.f;
  #pragma unroll 4
  for(int r=0;r<128;r++) s += bf2f(Hc[(long)(r0+r)*N_ + col]);
  partial[((long)c*16 + blockIdx.y)*N_ + col] = s;
}

// ---------------- dinv[c][m] = 1/(colsum - diag), guarded ----------------
__global__ void k_dinv(const u16* __restrict__ H, const float* __restrict__ partial,
                       float* __restrict__ dinvb){
  const int i = blockIdx.x*256 + threadIdx.x;  // c*N+m
  const int c = i >> 11, m = i & (N_-1);
  float s = 0.f;
  #pragma unroll
  for(int p=0;p<16;p++) s += partial[((long)c*16 + p)*N_ + m];
  s -= bf2f(H[c*NN_ + (long)m*N_ + m]);
  dinvb[i] = s > 0.f ? 1.f/s : 0.f;
}

// ---------------- H[j][i] = (j==i) ? 0 : H*dinv[i]  (in place) ----------------
__global__ void k_colscale(u16* __restrict__ H, const float* __restrict__ dinvb){
  const long i = (long)blockIdx.x*256 + threadIdx.x;
  const int c = blockIdx.y;
  const int j = (int)(i >> 11), ii = (int)(i & (N_-1));
  const long idx = c*NN_ + i;
  const float v = (j==ii) ? 0.f : bf2f(H[idx])*dinvb[c*N_ + ii];
  H[idx] = f2bf(v);
}

// ---------------- dis[c][j] = rsqrt(1 + rowsum(H2t[c][j][:])) ----------------
__global__ void k_gcnprep(const u16* __restrict__ H2t, float* __restrict__ disv){
  const int c = blockIdx.y, j = blockIdx.x;
  const u16* r = H2t + (c*(long)N_ + j)*N_;
  float s = 0.f;
  for(int i=threadIdx.x;i<N_;i+=256) s += bf2f(r[i]);
  __shared__ float red[256];
  red[threadIdx.x] = s;
  __syncthreads();
  for(int st=128; st>0; st>>=1){
    if(threadIdx.x < st) red[threadIdx.x] += red[threadIdx.x+st];
    __syncthreads();
  }
  if(threadIdx.x==0){
    const float deg = red[0] + 1.f;
    disv[c*N_ + j] = deg > 0.f ? rsqrtf(deg) : 0.f;
  }
}

// ---------------- Pd[c][j][i] = (H2t + I) * dis[i] ----------------
__global__ void k_pd(const u16* __restrict__ H2t, const float* __restrict__ disv,
                     u16* __restrict__ Pd){
  const long i = (long)blockIdx.x*256 + threadIdx.x;
  const int c = blockIdx.y;
  const int j = (int)(i >> 11);
  const int ii = (int)(i & (N_-1));
  const long idx = c*NN_ + i;
  const float v = bf2f(H2t[idx]) + (ii==j ? 1.f : 0.f);
  Pd[idx] = f2bf(v*disv[c*N_ + ii]);
}

// ---------------- transpose f32 in[R][Cc] -> bf16 out[Cc][R] ----------------
__global__ void k_transpose(const float* __restrict__ in, u16* __restrict__ out,
                            int R, int Cc){
  __shared__ float tt[32][33];
  const int ti = blockIdx.x, tj = blockIdx.y;
  const int x = threadIdx.x, y0 = threadIdx.y;
  #pragma unroll
  for(int i=0;i<4;i++){
    const int y = y0 + i*8;
    tt[y][x] = in[(long)(tj*32+y)*Cc + ti*32 + x];
  }
  __syncthreads();
  #pragma unroll
  for(int i=0;i<4;i++){
    const int y = y0 + i*8;
    out[(long)(ti*32+y)*R + tj*32 + x] = f2bf(tt[x][y]);
  }
}

// ---------------- cast f32 -> bf16 ----------------
__global__ void k_cast(const float* __restrict__ in, u16* __restrict__ out){
  const long i = (long)blockIdx.x*256 + threadIdx.x;
  out[i] = f2bf(in[i]);
}

// ---------------- bsum = bih + bhh; zero sync counters ----------------
__global__ void k_bias(const float* __restrict__ bih, const float* __restrict__ bhh,
                       float* __restrict__ bsum, u32* __restrict__ syncv){
  const int i = blockIdx.x*256 + threadIdx.x;
  bsum[i] = bih[i] + bhh[i];
  if(i < 64) syncv[i] = 0;
}

// ---------------- basket max-pool via active list ----------------
__global__ void k_pool(const float* __restrict__ seqs, const float* __restrict__ X_,
                       u16* __restrict__ bs){
  const int t = blockIdx.x, b = blockIdx.y;
  const float* mask = seqs + ((long)b*T_ + t)*N_;
  const int f = threadIdx.x;
  __shared__ int list[N_];
  __shared__ int cnt;
  if(f==0) cnt = 0;
  __syncthreads();
  for(int n0=f; n0<N_; n0+=256){
    if(mask[n0] > 0.f){
      int p = atomicAdd(&cnt, 1);
      list[p] = n0;
    }
  }
  __syncthreads();
  const int m = cnt;
  float mx = -3.4e38f;
  for(int i=0;i<m;i++)
    mx = fmaxf(mx, X_[(long)list[i]*WOUT_ + f]);
  bs[((long)b*T_ + t)*WOUT_ + f] = f2bf(m>0 ? mx : 0.f);
}

__global__ void k_zeropad(u16* __restrict__ bs){
  const int i = blockIdx.x*256 + threadIdx.x;
  bs[(long)BT_*WOUT_ + i] = 0;
}

// ---------------- pack Whh for k_lstm_all ----------------
// block g, local row lr = ui*4+gam, global row = gam*512+g*16+ui; element e holds k = e ^ ((lr&7)<<3)
__global__ void k_packWhh2(const float* __restrict__ Whh, u16* __restrict__ P){
  const long idx = (long)blockIdx.x*256 + threadIdx.x;  // 0..1048575
  const int e  = (int)(idx & 511);
  const int lr = (int)((idx >> 9) & 63);
  const int g  = (int)(idx >> 15);
  const int gam = lr & 3, ui = lr >> 2;
  const int grow = gam*512 + g*16 + ui;
  const int k = e ^ ((lr & 7) << 3);
  P[idx] = f2bf(Whh[(long)grow*512 + k]);
}

// ---------------- Hbuf init ----------------
__global__ void k_hinit(const float* __restrict__ h0, u16* __restrict__ Hb){
  const int idx = blockIdx.x*256 + threadIdx.x;  // 0..32767
  const int b = idx >> 9, u = idx & 511;
  Hb[(b << 9) + (u ^ ((b & 7) << 3))] = f2bf(h0[idx]);
}

// ---------------- persistent LSTM: 32 blocks, W staged once, grid sync per step ----------------
__global__ __launch_bounds__(256) void k_lstm_all(
    const u16* __restrict__ WhhB, const float* __restrict__ Gxt,
    const float* __restrict__ c0v, const int* __restrict__ seqlen,
    u16* __restrict__ Hglob, u32* __restrict__ syncv, float* __restrict__ act)
{
  __shared__ u16 Wl[64*512];
  __shared__ u16 Hl[64*512];
  const int g = blockIdx.x, tid = threadIdx.x;
  const int w = tid >> 6, l = tid & 63;
  const u16* Wsrc = WhhB + (long)g*(64*512);
  #pragma unroll
  for(int it=0; it<16; ++it){
    const int ch = it*4 + w;
    gload16(Wsrc + ch*512 + l*8, &Wl[ch*512]);
  }
  const int frow = l & 15, fkc = l >> 4;
  const int lr = w*16 + frow;
  const int ui = w*4 + (l>>4);
  const int ug = g*16 + ui;
  float cst[4];
  #pragma unroll
  for(int n=0;n<4;n++) cst[n] = c0v[(n*16 + (l&15))*U_ + ug];
  const int sl0 = seqlen[0*16 + (l&15)] - 1;   // not used; keep loads simple below

  for(int t=0; t<T_; ++t){
    const u16* Hin = Hglob + (t&1)*32768;
    #pragma unroll
    for(int it=0; it<16; ++it){
      const int ch = it*4 + w;
      gload16(Hin + ch*512 + l*8, &Hl[ch*512]);
    }
    __syncthreads();                 // compiler drains vmcnt before barrier

    f32x4 acc[4];
    #pragma unroll
    for(int n=0;n<4;n++) acc[n] = f32x4{0.f,0.f,0.f,0.f};
    #pragma unroll
    for(int kk=0; kk<16; ++kk){
      const int ke = kk*32 + fkc*8;
      bf16x8 a = *(const bf16x8*)&Wl[lr*512 + (ke ^ ((lr&7)<<3))];
      #pragma unroll
      for(int n=0;n<4;n++){
        const int b = n*16 + frow;
        bf16x8 bb = *(const bf16x8*)&Hl[b*512 + (ke ^ ((b&7)<<3))];
        acc[n] = __builtin_amdgcn_mfma_f32_16x16x32_bf16(a, bb, acc[n], 0, 0, 0);
      }
    }

    u16* Hout = Hglob + ((t+1)&1)*32768;
    const float* gx = Gxt + (long)t*2048*64;
    #pragma unroll
    for(int n=0;n<4;n++){
      const int b = n*16 + (l&15);
      const float a0 = acc[n][0] + gx[(0*U_+ug)*64 + b];
      const float a1 = acc[n][1] + gx[(1*U_+ug)*64 + b];
      const float a2 = acc[n][2] + gx[(2*U_+ug)*64 + b];
      const float a3 = acc[n][3] + gx[(3*U_+ug)*64 + b];
      const float ig = 1.f/(1.f + expf(-a0));
      const float fg = 1.f/(1.f + expf(-a1));
      const float gg = tanhf(a2);
      const float og = 1.f/(1.f + expf(-a3));
      const float c = fg*cst[n] + ig*gg;
      const float h = og*tanhf(c);
      cst[n] = c;
      Hout[(b << 9) + (ug ^ ((b & 7) << 3))] = f2bf(h);
      if(seqlen[b] - 1 == t) act[b*U_ + ug] = h;
    }
    (void)sl0;
    __syncthreads();                 // all waves' stores drained (vmcnt 0)
    if(tid == 0){
      __hip_atomic_fetch_add(&syncv[t], 1u, __ATOMIC_ACQ_REL, __HIP_MEMORY_SCOPE_AGENT);
      while(__hip_atomic_load(&syncv[t], __ATOMIC_ACQUIRE, __HIP_MEMORY_SCOPE_AGENT) < 32u){
        __builtin_amdgcn_s_sleep(8);
      }
    }
    __syncthreads();                 // whole block waits; caches invalidated by tid0's acquire
  }
}

// ---------------- out[b][n] = sigmoid(actual[b] . sWt[:,n])  (f32 out) ----------------
__global__ void k_score(const float* __restrict__ actual, const u16* __restrict__ sWt,
                        float* __restrict__ out){
  const int n = blockIdx.x*256 + threadIdx.x;
  const int b = blockIdx.y;
  const float* ab = actual + (long)b*U_;
  float s = 0.f;
  for(int uu=0; uu<U_; uu++) s += ab[uu]*bf2f(sWt[(long)uu*N_ + n]);
  out[(long)b*N_ + n] = 1.f/(1.f + expf(-s));
}

extern "C" void kernel_launch(void* const* d_in, const int* in_sizes, int n_in,
                              void* d_out, int out_size, void* d_ws, size_t ws_size,
                              hipStream_t stream){
  (void)in_sizes; (void)n_in; (void)out_size; (void)ws_size;
  const float* A      = (const float*)d_in[0];
  const float* X      = (const float*)d_in[1];
  const float* seqs   = (const float*)d_in[2];
  const int*   seqlen = (const int*)d_in[3];
  const float* h0     = (const float*)d_in[4];
  const float* c0     = (const float*)d_in[5];
  const float* gtw1   = (const float*)d_in[6];
  const float* gtw2   = (const float*)d_in[7];
  const float* gtw3   = (const float*)d_in[8];
  const float* gcnW   = (const float*)d_in[9];
  const float* gcnB   = (const float*)d_in[10];
  const float* lin1W  = (const float*)d_in[11];
  const float* lin1B  = (const float*)d_in[12];
  const float* Wih    = (const float*)d_in[13];
  const float* Whh    = (const float*)d_in[14];
  const float* bihp   = (const float*)d_in[15];
  const float* bhhp   = (const float*)d_in[16];
  const float* scoreW = (const float*)d_in[17];

  char* ws = (char*)d_ws;
  u16* buf0 = (u16*)(ws + 0);
  u16* buf1 = (u16*)(ws + 16777216);
  u16* buf2 = (u16*)(ws + 33554432);
  char* S0  = ws + 50331648;
  float* filt  = (float*)(S0 + 0);
  float* disv  = (float*)(S0 + 1024);
  u16*  Wt     = (u16*) (S0 + 17408);
  u16*  XWt    = (u16*) (S0 + 148480);
  u16*  catb   = (u16*) (S0 + 1197056);
  u16*  l1Wt   = (u16*) (S0 + 3294208);
  float* Xo    = (float*)(S0 + 3556352);
  u16*  bs     = (u16*) (S0 + 5653504);
  float* act   = (float*)(S0 + 7357440);
  u16*  sWt    = (u16*) (S0 + 7488512);
  u16*  WhhB   = (u16*) (S0 + 9585664);
  u16*  Xbf    = (u16*) (S0 + 11682816);
  u16*  Wihbf  = (u16*) (S0 + 12731392);
  float* bsum  = (float*)(S0 + 13779968);
  u16*  Hglob  = (u16*) (S0 + 13788160);   // 2 x 64KB double buffer
  u32*  syncv  = (u32*) (S0 + 13919232);   // 64 counters
  float* degp  = (float*)(S0 + 14050304);
  float* dinvb = (float*)(S0 + 14312448);
  u16* HA   = buf0;
  u16* HBt  = buf1;
  u16* Hb   = buf2;
  u16* HB2t = buf0;
  u16* H2t  = buf1;
  u16* Pd   = buf1;
  float* Gxt = (float*)ws;   // 26.2 MiB, after buf0/buf1 dead

  k_filters<<<1, 64, 0, stream>>>(gtw1, gtw2, gtw3, filt);
  k_combineAll<<<dim3(N_/32, N_/32), dim3(32,8), 0, stream>>>(A, filt, HA, HBt);
  k_transpose<<<dim3(WOUT_/32, WIN_/32), dim3(32,8), 0, stream>>>(gcnW, Wt, WIN_, WOUT_);
  k_transpose<<<dim3(WOUT_/32, (C_*WOUT_)/32), dim3(32,8), 0, stream>>>(lin1W, l1Wt, C_*WOUT_, WOUT_);
  k_transpose<<<dim3(U_/32, N_/32), dim3(32,8), 0, stream>>>(scoreW, sWt, N_, U_);
  k_cast<<<dim3((N_*WIN_)/256), 256, 0, stream>>>(X, Xbf);
  k_cast<<<dim3((4*U_*WOUT_)/256), 256, 0, stream>>>(Wih, Wihbf);
  k_bias<<<dim3((4*U_)/256), 256, 0, stream>>>(bihp, bhhp, bsum, syncv);
  // H = HA @ HB
  gemm_bt<1><<<dim3(16,16,C_), 256, 0, stream>>>(HA, HBt, Hb, N_, N_, NN_, NN_, NN_, nullptr, 0, nullptr);
  // col-normalize Hb (parallel)
  k_degpart<<<dim3(8, 16, C_), 256, 0, stream>>>(Hb, degp);
  k_dinv<<<dim3(16), 256, 0, stream>>>(Hb, degp, dinvb);
  k_colscale<<<dim3(NN_/256, C_), 256, 0, stream>>>(Hb, dinvb);
  k_combineT2<<<dim3(N_/32, N_/32), dim3(32,8), 0, stream>>>(A, filt + 2*C_*E_, HB2t);
  // H2t[m][n] = sum_k HB2t[m][k] * Hn[n][k]
  gemm_bt<1><<<dim3(16,16,C_), 256, 0, stream>>>(HB2t, Hb, H2t, N_, N_, NN_, NN_, NN_, nullptr, 0, nullptr);
  k_gcnprep<<<dim3(N_, C_), 256, 0, stream>>>(H2t, disv);
  k_pd<<<dim3(NN_/256, C_), 256, 0, stream>>>(H2t, disv, Pd);
  // XWt[f][node]
  gemm_bt<1><<<dim3(N_/128, WOUT_/128, 1), 256, 0, stream>>>(Wt, Xbf, XWt, WIN_, N_, 0, 0, 0, nullptr, 0, nullptr);
  // catb[t][c*256+f] = relu(dis[t]*(Pd x XWt) + gcn_b)
  gemm_bt<2><<<dim3(WOUT_/128, N_/128, C_), 256, 0, stream>>>(Pd, XWt, catb, N_, C_*WOUT_, NN_, 0, WOUT_, disv, N_, gcnB);
  // X_ = cat x lin1_W + lin1_b (f32)
  gemm_bt<3><<<dim3(WOUT_/128, N_/128, 1), 256, 0, stream>>>(catb, l1Wt, Xo, C_*WOUT_, WOUT_, 0, 0, 0, nullptr, 0, lin1B);
  k_zeropad<<<dim3((BTP_-BT_)*WOUT_/256), 256, 0, stream>>>(bs);
  k_pool<<<dim3(T_, B_), 256, 0, stream>>>(seqs, Xo, bs);
  // Gxt[(t*2048+r)*64+b] = bs[bt] . Wih[r] + bsum[r]
  gemm_bt<4><<<dim3((4*U_)/128, BTP_/128, 1), 256, 0, stream>>>(bs, Wihbf, Gxt, WOUT_, 0, 0, 0, 0, nullptr, 0, bsum);
  k_packWhh2<<<dim3(4096), 256, 0, stream>>>(Whh, WhhB);
  k_hinit<<<dim3(128), 256, 0, stream>>>(h0, Hglob);
  k_lstm_all<<<dim3(32), 256, 0, stream>>>(WhhB, Gxt, c0, seqlen, Hglob, syncv, act);
  k_score<<<dim3(N_/256, B_), 256, 0, stream>>>(act, sWt, (float*)d_out);
}